// Round 6
// baseline (226.971 us; speedup 1.0000x reference)
//
#include <hip/hip_runtime.h>
#include <hip/hip_fp16.h>
#include <math.h>

// clDice loss on 32x1x512x512: sigmoid + dice + 10x soft-skeletonize + skel dice.
// R1: per-block partials (1059 -> 466 us). R3: fused 2 iters/kernel via LDS (485).
// R5: 256 thr/block (316). R7: fp16 ping-pong + fp16 LDS B (262).
// R9: packed fp16 stencil (265). R10: 8-px quantum + 64x128 tile (227).
// R11: DMA fill + batched MLP fill in k_first (220). R12: tile pairing neutral.
// R13: fuse 4 iters/pass, 5 passes -> 3 (221): now VALU/issue-bound again
//      (VALUBusy 58%, HBM 8%); SQ_LDS_BANK_CONFLICT 2.14M.
// R14: kill stage1's 4-way LDS bank conflict: A4P 80->84. 84=4*21 keeps the
//      global_load_lds contiguity invariant (byte off = 16*(21r+q) = 16*i,
//      21 slots/row = exact 168px fill width); strips (row dist 6) now at bank
//      offsets {0,24,16,8} (was all 0 -> 4-way, 1.58x per m136). Zero VALU cost.
//      Also merge the two finalize kernels (-1 launch).

#define H 512
#define W 512
#define IMG (H * W)
#define NIMG 64
#define NPRED 32

// k_first (2-iter) geometry
#define APU 72      // A row pitch in uints; uint u <-> col tileX-8+2u
#define AROWS 74    // row r <-> gy = tileY + r - 4; data rows 0..71 (72,73 pad)
#define FILLN (AROWS * 18)
// final-stage input (old B / fused D): 68 rows x 68 uints; u <-> col tileX-4+2u
#define DPU 68
// fused 4-iter geometry
#define A4P 84      // A4 pitch (21 uint4 slots/row); uint u <-> col tileX-16+2u
#define A4R 82      // 80 data rows (gy = tileY+r-8) + 2 pad rows
#define B4P 76      // B4: 76 rows (gy = tileY+br-6), cols tileX-12+2u
#define C4P 72      // C4 (aliases A4): 72 rows (+2 pad overread), cols tileX-8+2u
#define FILL4N 1680 // 80 rows x 21 uint4-slots

#define PINF2 0x7C007C00u   // +inf,+inf (erosion-neutral pad)
#define NINF2 0xFC00FC00u   // -inf,-inf (dilation-neutral mask)
#define ONE2  0x3C003C00u   // 1.0,1.0

typedef _Float16 f16;
typedef _Float16 h2 __attribute__((ext_vector_type(2)));
typedef __fp16 fp16v2 __attribute__((ext_vector_type(2)));

__device__ __forceinline__ float2 unpack2(uint u) {
    fp16v2 h = __builtin_bit_cast(fp16v2, u);
    return make_float2((float)h.x, (float)h.y);
}
__device__ __forceinline__ uint pack2(float a, float b) {
    fp16v2 h = __builtin_amdgcn_cvt_pkrtz(a, b);
    return __builtin_bit_cast(uint, h);
}
__device__ __forceinline__ uint pmin(uint a, uint b) {
    uint d; asm("v_pk_min_f16 %0, %1, %2" : "=v"(d) : "v"(a), "v"(b)); return d;
}
__device__ __forceinline__ uint pmax(uint a, uint b) {
    uint d; asm("v_pk_max_f16 %0, %1, %2" : "=v"(d) : "v"(a), "v"(b)); return d;
}
// (hi<<16)|(lo>>16): odd-aligned fp16 pair from two even-aligned pairs
__device__ __forceinline__ uint abit(uint hi, uint lo) {
    return __builtin_amdgcn_alignbit(hi, lo, 16);
}

// async global->LDS DMA, 16B per lane (dest = wave-uniform base + lane*16).
__device__ __forceinline__ void lds_dma16(uint* l, const void* g) {
    __builtin_amdgcn_global_load_lds(
        (__attribute__((address_space(1))) void*)(g),
        (__attribute__((address_space(3))) void*)(l), 16, 0, 0);
}

__device__ __forceinline__ float wsum64(float v) {
#pragma unroll
    for (int o = 32; o > 0; o >>= 1) v += __shfl_down(v, o);
    return v;
}
__device__ __forceinline__ float wsum32(float v) {
#pragma unroll
    for (int o = 16; o > 0; o >>= 1) v += __shfl_down(v, o, 32);
    return v;
}

// Horizontal 3-min at 6 aligned pairs (cols c0-2..c0+9) from 8 uints (cols
// c0-4..c0+11); p points at the uint of col c0-4 (16B-aligned by construction).
__device__ __forceinline__ void hmin8p(const uint* __restrict__ p, uint m[6], uint sc[4]) {
    uint4 w0 = *(const uint4*)(p);
    uint4 w1 = *(const uint4*)(p + 4);
    uint w[8] = {w0.x, w0.y, w0.z, w0.w, w1.x, w1.y, w1.z, w1.w};
    sc[0] = w[2]; sc[1] = w[3]; sc[2] = w[4]; sc[3] = w[5];
    uint s[7];
#pragma unroll
    for (int j = 0; j < 7; j++) s[j] = abit(w[j + 1], w[j]);
#pragma unroll
    for (int i = 0; i < 6; i++) m[i] = pmin(s[i], pmin(w[i + 1], s[i + 1]));
}

template<bool EDGE>
__device__ __forceinline__ void erode8(const uint a[6], const uint b[6], const uint c[6],
                                       bool rowok, const bool* eok, uint e[6]) {
#pragma unroll
    for (int i = 0; i < 6; i++) {
        uint v = pmin(a[i], pmin(b[i], c[i]));
        e[i] = EDGE ? ((rowok && eok[i]) ? v : NINF2) : v;
    }
}

__device__ __forceinline__ void hmax8(const uint e[6], uint hx[4], uint ec[4]) {
    uint a[5];
#pragma unroll
    for (int j = 0; j < 5; j++) a[j] = abit(e[j + 1], e[j]);
#pragma unroll
    for (int p = 0; p < 4; p++) {
        hx[p] = pmax(a[p], pmax(e[p + 1], a[p + 1]));
        ec[p] = e[p + 1];
    }
}

// skel update, packed fp16: o = clamp(s - (s-e)*t, 0, 1).
__device__ __forceinline__ uint upd_pair(uint s, uint ec, uint t) {
    h2 sh = __builtin_bit_cast(h2, s);
    h2 eh = __builtin_bit_cast(h2, ec);
    h2 th = __builtin_bit_cast(h2, t);
    h2 o = sh - (sh - eh) * th;
    return pmin(pmax(__builtin_bit_cast(uint, o), 0u), ONE2);
}

// Generic one-iteration stage: in(pitch PIN, rows <-> gy=tileY+r-RO-2, cols
// tileX-(2*RO+4)+2u) -> out(pitch POUT, rows <-> gy=tileY+br-RO, cols
// tileX-2*RO+2u). NG 8-col groups, NSTRIP strips of SROWS rows, NROWS outputs.
// All ds_read_b128 16B-aligned: p-index = 4g at every depth.
template<bool EDGE, int PIN, int POUT, int NG, int NSTRIP, int SROWS, int NROWS, int RO>
__device__ void stageN(const uint* __restrict__ in, uint* __restrict__ out,
                       int tileX, int tileY, int tid) {
    if (tid >= NSTRIP * NG) return;
    const int s = tid / NG;
    const int g = tid - NG * s;
    const int c0 = tileX - 2 * RO + 8 * g;   // global col of group's first output
    const int ys = tileY + SROWS * s - RO;   // global row of strip's first output
    bool eok[6], wok[4];
    if (EDGE) {
#pragma unroll
        for (int i = 0; i < 6; i++) eok[i] = ((unsigned)(c0 - 2 + 2 * i) < (unsigned)W);
#pragma unroll
        for (int p = 0; p < 4; p++) wok[p] = ((unsigned)(c0 + 2 * p) < (unsigned)W);
    }
    const int lr = SROWS * s + 2;
    const uint* Ab = in + 4 * g;
    uint m[3][6], sc[3][4], hx[3][4], e[6], ec_cur[4], ec_nxt[4], tsc[4];
    hmin8p(Ab + (lr - 2) * PIN, m[0], tsc);
    hmin8p(Ab + (lr - 1) * PIN, m[1], tsc);
    hmin8p(Ab + (lr + 0) * PIN, m[2], sc[0]);
    erode8<EDGE>(m[0], m[1], m[2], (unsigned)(ys - 1) < (unsigned)H, eok, e);
    hmax8(e, hx[0], ec_nxt);
    hmin8p(Ab + (lr + 1) * PIN, m[0], sc[1]);
    erode8<EDGE>(m[1], m[2], m[0], (unsigned)ys < (unsigned)H, eok, e);
    hmax8(e, hx[1], ec_cur);
#pragma unroll
    for (int k = 0; k < SROWS; k++) {
        hmin8p(Ab + (lr + 2 + k) * PIN, m[(k + 1) % 3], sc[(2 + k) % 3]);
        erode8<EDGE>(m[(k + 2) % 3], m[k % 3], m[(k + 1) % 3],
                     (unsigned)(ys + k + 1) < (unsigned)H, eok, e);
        hmax8(e, hx[(k + 2) % 3], ec_nxt);
        const int br = SROWS * s + k;
        if (NSTRIP * SROWS <= NROWS || br < NROWS) {   // constexpr-skipped when exact
            const bool rin = EDGE ? ((unsigned)(ys + k) < (unsigned)H) : true;
            uint o[4];
#pragma unroll
            for (int p = 0; p < 4; p++) {
                uint t = pmax(hx[k % 3][p], pmax(hx[(k + 1) % 3][p], hx[(k + 2) % 3][p]));
                uint v = upd_pair(sc[k % 3][p], ec_cur[p], t);
                o[p] = EDGE ? ((rin && wok[p]) ? v : PINF2) : v;
            }
            *(uint4*)(out + br * POUT + 4 * g) = make_uint4(o[0], o[1], o[2], o[3]);
        }
#pragma unroll
        for (int p = 0; p < 4; p++) ec_cur[p] = ec_nxt[p];
    }
}

// Final stage: D(fp16, pitch DPU) -> 64x128 interior (fp16 global or regs).
// 256 items = 16 groups(8 cols) x 16 strips(4 rows).
template<bool EDGE, bool TOREG>
__device__ void stage2(const uint* __restrict__ Du, int tileX, int tileY, int tid,
                       f16* __restrict__ gdst, uint* __restrict__ oreg) {
    const int g = tid & 15;
    const int ty = tid >> 4;
    const int X = tileX + 8 * g;
    const int gy0 = tileY + 4 * ty;
    const int rb = 4 * ty + 2;
    bool eok[6];
    if (EDGE) {
#pragma unroll
        for (int i = 0; i < 6; i++) eok[i] = ((unsigned)(X - 2 + 2 * i) < (unsigned)W);
    }
    const uint* Bb = Du + 4 * g;
    uint m[3][6], sc[3][4], hx[3][4], e[6], ec_cur[4], ec_nxt[4], tsc[4];
    hmin8p(Bb + (rb - 2) * DPU, m[0], tsc);
    hmin8p(Bb + (rb - 1) * DPU, m[1], tsc);
    hmin8p(Bb + (rb + 0) * DPU, m[2], sc[0]);
    erode8<EDGE>(m[0], m[1], m[2], (unsigned)(gy0 - 1) < (unsigned)H, eok, e);
    hmax8(e, hx[0], ec_nxt);
    hmin8p(Bb + (rb + 1) * DPU, m[0], sc[1]);
    erode8<EDGE>(m[1], m[2], m[0], true, eok, e);
    hmax8(e, hx[1], ec_cur);
#pragma unroll
    for (int k = 0; k < 4; k++) {
        hmin8p(Bb + (rb + 2 + k) * DPU, m[(k + 1) % 3], sc[(2 + k) % 3]);
        erode8<EDGE>(m[(k + 2) % 3], m[k % 3], m[(k + 1) % 3],
                     (unsigned)(gy0 + k + 1) < (unsigned)H, eok, e);
        hmax8(e, hx[(k + 2) % 3], ec_nxt);
        uint o[4];
#pragma unroll
        for (int p = 0; p < 4; p++) {
            uint t = pmax(hx[k % 3][p], pmax(hx[(k + 1) % 3][p], hx[(k + 2) % 3][p]));
            o[p] = upd_pair(sc[k % 3][p], ec_cur[p], t);
        }
        if (TOREG) {
#pragma unroll
            for (int p = 0; p < 4; p++) oreg[4 * k + p] = o[p];
        } else {
            *(uint4*)(gdst + (size_t)(gy0 + k) * W + X) = make_uint4(o[0], o[1], o[2], o[3]);
        }
#pragma unroll
        for (int p = 0; p < 4; p++) ec_cur[p] = ec_nxt[p];
    }
}

// Fill packed-fp16 LDS A (k_first geometry) from fp32 source (optional sigmoid);
// fuse dice partials over the 64x128 interior (fp32 pre-pack -> exact dice).
// Batched 2 x 3 load-then-store (MLP latency hiding).
template<bool EDGE, int SIG>
__device__ float2 fillA_f32(uint* __restrict__ A, const float* __restrict__ src,
                            const float* __restrict__ tgt,
                            int tileX, int tileY, int tid) {
    float a = 0.0f, b = 0.0f;
#pragma unroll
    for (int hf = 0; hf < 2; hf++) {
        float4 v0[3], v1[3], t0[3], t1[3];
        bool ld[3];
#pragma unroll
        for (int j = 0; j < 3; j++) {
            const int i = tid + 256 * (3 * hf + j);
            const int r = i / 18;
            const int q = i - 18 * r;
            const int gy = tileY + r - 4;
            const int gx = tileX - 8 + 8 * q;
            bool ok = (i < FILLN);
            if (EDGE) ok = ok && (r < 72) && ((unsigned)gy < (unsigned)H) &&
                           ((unsigned)gx < (unsigned)W);
            ld[j] = ok;
            if (ok) {
                const float* sp = src + (size_t)gy * W + gx;
                v0[j] = *(const float4*)(sp);
                v1[j] = *(const float4*)(sp + 4);
                if (SIG) {
                    const float* tp = tgt + (size_t)gy * W + gx;
                    t0[j] = *(const float4*)(tp);
                    t1[j] = *(const float4*)(tp + 4);
                }
            }
        }
#pragma unroll
        for (int j = 0; j < 3; j++) {
            const int i = tid + 256 * (3 * hf + j);
            const int r = i / 18;
            const int q = i - 18 * r;
            if (i < FILLN) {
                uint4 w = make_uint4(PINF2, PINF2, PINF2, PINF2);
                if (ld[j]) {
                    float4 f0 = v0[j], f1 = v1[j];
                    if (SIG) {
                        f0.x = 1.0f / (1.0f + __expf(-f0.x));
                        f0.y = 1.0f / (1.0f + __expf(-f0.y));
                        f0.z = 1.0f / (1.0f + __expf(-f0.z));
                        f0.w = 1.0f / (1.0f + __expf(-f0.w));
                        f1.x = 1.0f / (1.0f + __expf(-f1.x));
                        f1.y = 1.0f / (1.0f + __expf(-f1.y));
                        f1.z = 1.0f / (1.0f + __expf(-f1.z));
                        f1.w = 1.0f / (1.0f + __expf(-f1.w));
                    }
                    if (((unsigned)(r - 4) < 64u) && ((unsigned)(q - 1) < 16u)) {
                        if (SIG) {
                            a += f0.x * t0[j].x + f0.y * t0[j].y + f0.z * t0[j].z +
                                 f0.w * t0[j].w + f1.x * t1[j].x + f1.y * t1[j].y +
                                 f1.z * t1[j].z + f1.w * t1[j].w;
                            b += f0.x + f0.y + f0.z + f0.w + f1.x + f1.y + f1.z + f1.w;
                        } else {
                            a += f0.x + f0.y + f0.z + f0.w + f1.x + f1.y + f1.z + f1.w;
                        }
                    }
                    w.x = pack2(f0.x, f0.y); w.y = pack2(f0.z, f0.w);
                    w.z = pack2(f1.x, f1.y); w.w = pack2(f1.z, f1.w);
                }
                *(uint4*)(A + r * APU + 4 * q) = w;
            }
        }
    }
    return make_float2(a, b);
}

// DMA fill of A4 (fused geometry, pitch 84 = 21 uint4 slots/row; byte offset
// 16*(21r+q) = 16*i keeps the wave-uniform-base+lane*16 contiguity). Source
// rows clamped into the image (replicate = SAME-pad-equivalent through masked
// erosion); fully-OOB x-slots (8-aligned, never straddling) write +inf.
__device__ __forceinline__ void dma4_item(uint* __restrict__ A,
                                          const f16* __restrict__ src,
                                          int tileX, int tileY, int i) {
    const int r = i / 21;
    const int q = i - 21 * r;
    const int gy = tileY + r - 8;
    const int gx = tileX - 16 + 8 * q;
    if (gx < 0 || gx >= W) {
        *(uint4*)(A + r * A4P + 4 * q) = make_uint4(PINF2, PINF2, PINF2, PINF2);
    } else {
        const int gyc = min(max(gy, 0), H - 1);
        lds_dma16(A + r * A4P + 4 * q, src + (size_t)gyc * W + gx);
    }
}
__device__ __forceinline__ void fill_dma4(uint* __restrict__ A, const f16* __restrict__ src,
                                          int tileX, int tileY, int tid) {
#pragma unroll
    for (int j = 0; j < 6; j++) dma4_item(A, src, tileX, tileY, tid + 256 * j);
    if (tid < FILL4N - 1536) dma4_item(A, src, tileX, tileY, tid + 1536);
}

// 4-iteration chain: A4 -> B4 -> C4(in A4) -> D(in B4) -> out.
// If PRE: issue the next tile's A4 DMA after s3's barrier (A4 dead; drains
// under s4's compute, retired by the caller's next __syncthreads()).
template<bool EDGE, bool TOREG, bool PRE>
__device__ void chain4(uint* __restrict__ A4, uint* __restrict__ B4,
                       int tileX, int tileY, int tid,
                       f16* __restrict__ dst, uint* __restrict__ oreg,
                       const f16* __restrict__ pre) {
    stageN<EDGE, A4P, B4P, 19, 13, 6, 76, 6>(A4, B4, tileX, tileY, tid);
    __syncthreads();
    stageN<EDGE, B4P, C4P, 18, 12, 6, 72, 4>(B4, A4, tileX, tileY, tid);
    __syncthreads();
    stageN<EDGE, C4P, DPU, 17, 14, 5, 68, 2>(A4, B4, tileX, tileY, tid);
    __syncthreads();
    if (PRE) fill_dma4(A4, pre, tileX, tileY, tid);
    stage2<EDGE, TOREG>(B4, tileX, tileY, tid, dst, oreg);
}

__device__ __forceinline__ bool is_edge() {
    return (blockIdx.x == 0) | (blockIdx.x == 3) | (blockIdx.y == 0) | (blockIdx.y == 7);
}

// ---- K1: sigmoid + dice partials (fused in fill) + iters 1,2 ----
__global__ __launch_bounds__(256, 4) void k_first(
    const float* __restrict__ logits, const float* __restrict__ target,
    f16* __restrict__ outb, float* __restrict__ parts0, float* __restrict__ parts1) {
    __shared__ __align__(16) uint A[AROWS * APU];
    __shared__ __align__(16) uint Bu[68 * DPU];
    __shared__ float red[8];
    const int img = blockIdx.z;
    const int tileX = blockIdx.x * 128, tileY = blockIdx.y * 64;
    const int tid = threadIdx.x;
    const bool pred = (img < NPRED);
    const bool edge = is_edge();
    float2 ab;
    if (edge) {
        if (pred) ab = fillA_f32<true, 1>(A, logits + (size_t)img * IMG,
                                          target + (size_t)img * IMG, tileX, tileY, tid);
        else      ab = fillA_f32<true, 0>(A, target + (size_t)(img - NPRED) * IMG,
                                          nullptr, tileX, tileY, tid);
    } else {
        if (pred) ab = fillA_f32<false, 1>(A, logits + (size_t)img * IMG,
                                           target + (size_t)img * IMG, tileX, tileY, tid);
        else      ab = fillA_f32<false, 0>(A, target + (size_t)(img - NPRED) * IMG,
                                           nullptr, tileX, tileY, tid);
    }
    __syncthreads();
    float a = wsum64(ab.x), b = wsum64(ab.y);
    if ((tid & 63) == 0) { red[tid >> 6] = a; red[4 + (tid >> 6)] = b; }
    if (edge) stageN<true, APU, DPU, 17, 14, 5, 68, 2>(A, Bu, tileX, tileY, tid);
    else      stageN<false, APU, DPU, 17, 14, 5, 68, 2>(A, Bu, tileX, tileY, tid);
    __syncthreads();
    if (tid == 0) {
        int bi = blockIdx.z * 32 + blockIdx.y * 4 + blockIdx.x;
        parts0[bi] = red[0] + red[1] + red[2] + red[3];
        parts1[bi] = red[4] + red[5] + red[6] + red[7];
    }
    if (edge) stage2<true, false>(Bu, tileX, tileY, tid, outb + (size_t)img * IMG, nullptr);
    else      stage2<false, false>(Bu, tileX, tileY, tid, outb + (size_t)img * IMG, nullptr);
}

// ---- K2: iters 3-6 in one pass, fp16 buf -> fp16 buf ----
__global__ __launch_bounds__(256, 3) void k_mid4(
    const f16* __restrict__ in, f16* __restrict__ outb) {
    __shared__ __align__(16) uint A4[A4R * A4P];
    __shared__ __align__(16) uint B4[76 * B4P];
    const int img = blockIdx.z;
    const int tileX = blockIdx.x * 128, tileY = blockIdx.y * 64;
    const int tid = threadIdx.x;
    const bool edge = is_edge();
    const f16* src = in + (size_t)img * IMG;
    f16* dst = outb + (size_t)img * IMG;
    fill_dma4(A4, src, tileX, tileY, tid);
    __syncthreads();
    if (edge) chain4<true, false, false>(A4, B4, tileX, tileY, tid, dst, nullptr, nullptr);
    else      chain4<false, false, false>(A4, B4, tileX, tileY, tid, dst, nullptr, nullptr);
}

// ---- K3: iters 7-10 for pred tile AND matching target tile; skel-dice partials.
// Target-tile DMA issues inside chain4 (after s3) to overlap with s4. ----
__global__ __launch_bounds__(256, 3) void k_last4(
    const f16* __restrict__ in, float* __restrict__ pA,
    float* __restrict__ pB, float* __restrict__ pC) {
    __shared__ __align__(16) uint A4[A4R * A4P];
    __shared__ __align__(16) uint B4[76 * B4P];
    __shared__ float red[12];
    const int img = blockIdx.z;                  // 0..31
    const int tileX = blockIdx.x * 128, tileY = blockIdx.y * 64;
    const int tid = threadIdx.x;
    const bool edge = is_edge();
    uint op[16], ot[16];
    const f16* tsrc = in + (size_t)(img + NPRED) * IMG;
    fill_dma4(A4, in + (size_t)img * IMG, tileX, tileY, tid);
    __syncthreads();
    if (edge) {
        chain4<true, true, true>(A4, B4, tileX, tileY, tid, nullptr, op, tsrc);
        __syncthreads();   // drain target DMA; all D-reads of pred retired
        chain4<true, true, false>(A4, B4, tileX, tileY, tid, nullptr, ot, nullptr);
    } else {
        chain4<false, true, true>(A4, B4, tileX, tileY, tid, nullptr, op, tsrc);
        __syncthreads();
        chain4<false, true, false>(A4, B4, tileX, tileY, tid, nullptr, ot, nullptr);
    }
    float a = 0.0f, b = 0.0f, c = 0.0f;
#pragma unroll
    for (int j = 0; j < 16; j++) {
        float2 p = unpack2(op[j]);
        float2 t = unpack2(ot[j]);
        a += p.x * t.x + p.y * t.y;
        b += p.x + p.y;
        c += t.x + t.y;
    }
    a = wsum64(a); b = wsum64(b); c = wsum64(c);
    if ((tid & 63) == 0) {
        red[tid >> 6] = a; red[4 + (tid >> 6)] = b; red[8 + (tid >> 6)] = c;
    }
    __syncthreads();
    if (tid == 0) {
        int bi = img * 32 + blockIdx.y * 4 + blockIdx.x;
        pA[bi] = red[0] + red[1] + red[2] + red[3];
        pB[bi] = red[4] + red[5] + red[6] + red[7];
        pC[bi] = red[8] + red[9] + red[10] + red[11];
    }
}

// ---- single finalize: per-image dice (32 imgs x 32 partials) + final means.
// 1024 threads: t>>5 = image, t&31 = partial slot; shfl width 32 keeps the two
// 32-lane halves of each wave on separate images. ----
__global__ __launch_bounds__(1024) void finalize(
    const float* __restrict__ parts0, const float* __restrict__ parts1,
    const float* __restrict__ pA, const float* __restrict__ pB,
    const float* __restrict__ pC, float* __restrict__ out) {
    __shared__ float sd[64];
    const int t = threadIdx.x;
    const int img = t >> 5;
    const int p = t & 31;
    float inter = wsum32(parts0[img * 32 + p]);
    float sp = wsum32(parts1[img * 32 + p]);
    float st = wsum32(parts0[(NPRED + img) * 32 + p]);
    float i2 = wsum32(pA[img * 32 + p]);
    float sp2 = wsum32(pB[img * 32 + p]);
    float st2 = wsum32(pC[img * 32 + p]);
    if (p == 0) {
        sd[img] = (float)((2.0 * (double)inter + 1e-5) / ((double)sp + (double)st + 1e-5));
        sd[32 + img] = (float)((2.0 * (double)i2 + 1e-5) / ((double)sp2 + (double)st2 + 1e-5));
    }
    __syncthreads();
    if (t < 64) {
        double d = (t < 32) ? (double)sd[t] : 0.0;
        double s2 = (t < 32) ? (double)sd[32 + t] : 0.0;
#pragma unroll
        for (int o = 32; o > 0; o >>= 1) { d += __shfl_down(d, o); s2 += __shfl_down(s2, o); }
        if (t == 0) {
            d *= (1.0 / 32.0); s2 *= (1.0 / 32.0);
            out[0] = (float)(0.5 * (1.0 - d) + 0.5 * (1.0 - s2));
            out[1] = (float)d;
            out[2] = (float)s2;
        }
    }
}

extern "C" void kernel_launch(void* const* d_in, const int* in_sizes, int n_in,
                              void* d_out, int out_size, void* d_ws, size_t ws_size,
                              hipStream_t stream) {
    (void)in_sizes; (void)n_in; (void)out_size; (void)ws_size;
    const float* logits = (const float*)d_in[0];
    const float* target = (const float*)d_in[1];
    float* out = (float*)d_out;
    f16* buf0 = (f16*)d_ws;                         // 64*262144 halves (33.5 MB)
    f16* buf1 = buf0 + (size_t)NIMG * IMG;
    float* parts0 = (float*)(buf1 + (size_t)NIMG * IMG);   // 2048
    float* parts1 = parts0 + 2048;                  // 2048
    float* pA = parts1 + 2048;                      // 1024
    float* pB = pA + 1024;
    float* pC = pB + 1024;

    dim3 blk(256, 1, 1);
    k_first<<<dim3(4, 8, NIMG), blk, 0, stream>>>(logits, target, buf0, parts0, parts1);
    k_mid4<<<dim3(4, 8, NIMG), blk, 0, stream>>>(buf0, buf1);         // iters 3-6
    k_last4<<<dim3(4, 8, NPRED), blk, 0, stream>>>(buf1, pA, pB, pC); // iters 7-10 + partials
    finalize<<<1, 1024, 0, stream>>>(parts0, parts1, pA, pB, pC, out);
}

// Round 7
// 219.651 us; speedup vs baseline: 1.0333x; 1.0333x over previous
//
#include <hip/hip_runtime.h>
#include <hip/hip_fp16.h>
#include <math.h>

// clDice loss on 32x1x512x512: sigmoid + dice + 10x soft-skeletonize + skel dice.
// R1: per-block partials (1059 -> 466 us). R3: fused 2 iters/kernel via LDS (485).
// R5: 256 thr/block (316). R7: fp16 ping-pong + fp16 LDS B (262).
// R9: packed fp16 stencil (265). R10: 8-px quantum + 64x128 tile (227).
// R11: DMA fill + batched MLP fill in k_first (220). R12: tile pairing neutral.
// R13: fuse 4 iters/pass, 5 passes -> 3 (221). VALUBusy 58%, HBM 8%.
// R14: A4P 80->84 for stage1 bank conflicts: WRONG THEORY -- conflicts unchanged
//      (they're inherent multi-row b128 span, ~6% floor), total regressed (227).
// R15: revert to R13 geometry (A4P=80); keep R14's merged finalize (-1 launch).
//      Plateau analysis: remaining gap = barrier/tail/issue ceiling (~58%) at
//      3 blocks/CU + fixed 42us harness memset; all structural variants measured
//      220 +/- 7.

#define H 512
#define W 512
#define IMG (H * W)
#define NIMG 64
#define NPRED 32

// k_first (2-iter) geometry
#define APU 72      // A row pitch in uints; uint u <-> col tileX-8+2u
#define AROWS 74    // row r <-> gy = tileY + r - 4; data rows 0..71 (72,73 pad)
#define FILLN (AROWS * 18)
// final-stage input (old B / fused D): 68 rows x 68 uints; u <-> col tileX-4+2u
#define DPU 68
// fused 4-iter geometry
#define A4P 80      // A4: 80 data rows (gy = tileY+r-8), cols tileX-16+2u, u 0..79
#define A4R 82      // +2 pad rows for s1 rolling overread
#define B4P 76      // B4: 76 rows (gy = tileY+br-6), cols tileX-12+2u
#define C4P 72      // C4 (aliases A4): 72 rows (+2 pad overread), cols tileX-8+2u
#define FILL4N 1600 // 80 rows x 20 uint4-slots

#define PINF2 0x7C007C00u   // +inf,+inf (erosion-neutral pad)
#define NINF2 0xFC00FC00u   // -inf,-inf (dilation-neutral mask)
#define ONE2  0x3C003C00u   // 1.0,1.0

typedef _Float16 f16;
typedef _Float16 h2 __attribute__((ext_vector_type(2)));
typedef __fp16 fp16v2 __attribute__((ext_vector_type(2)));

__device__ __forceinline__ float2 unpack2(uint u) {
    fp16v2 h = __builtin_bit_cast(fp16v2, u);
    return make_float2((float)h.x, (float)h.y);
}
__device__ __forceinline__ uint pack2(float a, float b) {
    fp16v2 h = __builtin_amdgcn_cvt_pkrtz(a, b);
    return __builtin_bit_cast(uint, h);
}
__device__ __forceinline__ uint pmin(uint a, uint b) {
    uint d; asm("v_pk_min_f16 %0, %1, %2" : "=v"(d) : "v"(a), "v"(b)); return d;
}
__device__ __forceinline__ uint pmax(uint a, uint b) {
    uint d; asm("v_pk_max_f16 %0, %1, %2" : "=v"(d) : "v"(a), "v"(b)); return d;
}
// (hi<<16)|(lo>>16): odd-aligned fp16 pair from two even-aligned pairs
__device__ __forceinline__ uint abit(uint hi, uint lo) {
    return __builtin_amdgcn_alignbit(hi, lo, 16);
}

// async global->LDS DMA, 16B per lane (dest = wave-uniform base + lane*16).
__device__ __forceinline__ void lds_dma16(uint* l, const void* g) {
    __builtin_amdgcn_global_load_lds(
        (__attribute__((address_space(1))) void*)(g),
        (__attribute__((address_space(3))) void*)(l), 16, 0, 0);
}

__device__ __forceinline__ float wsum64(float v) {
#pragma unroll
    for (int o = 32; o > 0; o >>= 1) v += __shfl_down(v, o);
    return v;
}
__device__ __forceinline__ float wsum32(float v) {
#pragma unroll
    for (int o = 16; o > 0; o >>= 1) v += __shfl_down(v, o, 32);
    return v;
}

// Horizontal 3-min at 6 aligned pairs (cols c0-2..c0+9) from 8 uints (cols
// c0-4..c0+11); p points at the uint of col c0-4 (16B-aligned by construction).
__device__ __forceinline__ void hmin8p(const uint* __restrict__ p, uint m[6], uint sc[4]) {
    uint4 w0 = *(const uint4*)(p);
    uint4 w1 = *(const uint4*)(p + 4);
    uint w[8] = {w0.x, w0.y, w0.z, w0.w, w1.x, w1.y, w1.z, w1.w};
    sc[0] = w[2]; sc[1] = w[3]; sc[2] = w[4]; sc[3] = w[5];
    uint s[7];
#pragma unroll
    for (int j = 0; j < 7; j++) s[j] = abit(w[j + 1], w[j]);
#pragma unroll
    for (int i = 0; i < 6; i++) m[i] = pmin(s[i], pmin(w[i + 1], s[i + 1]));
}

template<bool EDGE>
__device__ __forceinline__ void erode8(const uint a[6], const uint b[6], const uint c[6],
                                       bool rowok, const bool* eok, uint e[6]) {
#pragma unroll
    for (int i = 0; i < 6; i++) {
        uint v = pmin(a[i], pmin(b[i], c[i]));
        e[i] = EDGE ? ((rowok && eok[i]) ? v : NINF2) : v;
    }
}

__device__ __forceinline__ void hmax8(const uint e[6], uint hx[4], uint ec[4]) {
    uint a[5];
#pragma unroll
    for (int j = 0; j < 5; j++) a[j] = abit(e[j + 1], e[j]);
#pragma unroll
    for (int p = 0; p < 4; p++) {
        hx[p] = pmax(a[p], pmax(e[p + 1], a[p + 1]));
        ec[p] = e[p + 1];
    }
}

// skel update, packed fp16: o = clamp(s - (s-e)*t, 0, 1).
__device__ __forceinline__ uint upd_pair(uint s, uint ec, uint t) {
    h2 sh = __builtin_bit_cast(h2, s);
    h2 eh = __builtin_bit_cast(h2, ec);
    h2 th = __builtin_bit_cast(h2, t);
    h2 o = sh - (sh - eh) * th;
    return pmin(pmax(__builtin_bit_cast(uint, o), 0u), ONE2);
}

// Generic one-iteration stage: in(pitch PIN, rows <-> gy=tileY+r-RO-2, cols
// tileX-(2*RO+4)+2u) -> out(pitch POUT, rows <-> gy=tileY+br-RO, cols
// tileX-2*RO+2u). NG 8-col groups, NSTRIP strips of SROWS rows, NROWS outputs.
// All ds_read_b128 16B-aligned: p-index = 4g at every depth.
template<bool EDGE, int PIN, int POUT, int NG, int NSTRIP, int SROWS, int NROWS, int RO>
__device__ void stageN(const uint* __restrict__ in, uint* __restrict__ out,
                       int tileX, int tileY, int tid) {
    if (tid >= NSTRIP * NG) return;
    const int s = tid / NG;
    const int g = tid - NG * s;
    const int c0 = tileX - 2 * RO + 8 * g;   // global col of group's first output
    const int ys = tileY + SROWS * s - RO;   // global row of strip's first output
    bool eok[6], wok[4];
    if (EDGE) {
#pragma unroll
        for (int i = 0; i < 6; i++) eok[i] = ((unsigned)(c0 - 2 + 2 * i) < (unsigned)W);
#pragma unroll
        for (int p = 0; p < 4; p++) wok[p] = ((unsigned)(c0 + 2 * p) < (unsigned)W);
    }
    const int lr = SROWS * s + 2;
    const uint* Ab = in + 4 * g;
    uint m[3][6], sc[3][4], hx[3][4], e[6], ec_cur[4], ec_nxt[4], tsc[4];
    hmin8p(Ab + (lr - 2) * PIN, m[0], tsc);
    hmin8p(Ab + (lr - 1) * PIN, m[1], tsc);
    hmin8p(Ab + (lr + 0) * PIN, m[2], sc[0]);
    erode8<EDGE>(m[0], m[1], m[2], (unsigned)(ys - 1) < (unsigned)H, eok, e);
    hmax8(e, hx[0], ec_nxt);
    hmin8p(Ab + (lr + 1) * PIN, m[0], sc[1]);
    erode8<EDGE>(m[1], m[2], m[0], (unsigned)ys < (unsigned)H, eok, e);
    hmax8(e, hx[1], ec_cur);
#pragma unroll
    for (int k = 0; k < SROWS; k++) {
        hmin8p(Ab + (lr + 2 + k) * PIN, m[(k + 1) % 3], sc[(2 + k) % 3]);
        erode8<EDGE>(m[(k + 2) % 3], m[k % 3], m[(k + 1) % 3],
                     (unsigned)(ys + k + 1) < (unsigned)H, eok, e);
        hmax8(e, hx[(k + 2) % 3], ec_nxt);
        const int br = SROWS * s + k;
        if (NSTRIP * SROWS <= NROWS || br < NROWS) {   // constexpr-skipped when exact
            const bool rin = EDGE ? ((unsigned)(ys + k) < (unsigned)H) : true;
            uint o[4];
#pragma unroll
            for (int p = 0; p < 4; p++) {
                uint t = pmax(hx[k % 3][p], pmax(hx[(k + 1) % 3][p], hx[(k + 2) % 3][p]));
                uint v = upd_pair(sc[k % 3][p], ec_cur[p], t);
                o[p] = EDGE ? ((rin && wok[p]) ? v : PINF2) : v;
            }
            *(uint4*)(out + br * POUT + 4 * g) = make_uint4(o[0], o[1], o[2], o[3]);
        }
#pragma unroll
        for (int p = 0; p < 4; p++) ec_cur[p] = ec_nxt[p];
    }
}

// Final stage: D(fp16, pitch DPU) -> 64x128 interior (fp16 global or regs).
// 256 items = 16 groups(8 cols) x 16 strips(4 rows).
template<bool EDGE, bool TOREG>
__device__ void stage2(const uint* __restrict__ Du, int tileX, int tileY, int tid,
                       f16* __restrict__ gdst, uint* __restrict__ oreg) {
    const int g = tid & 15;
    const int ty = tid >> 4;
    const int X = tileX + 8 * g;
    const int gy0 = tileY + 4 * ty;
    const int rb = 4 * ty + 2;
    bool eok[6];
    if (EDGE) {
#pragma unroll
        for (int i = 0; i < 6; i++) eok[i] = ((unsigned)(X - 2 + 2 * i) < (unsigned)W);
    }
    const uint* Bb = Du + 4 * g;
    uint m[3][6], sc[3][4], hx[3][4], e[6], ec_cur[4], ec_nxt[4], tsc[4];
    hmin8p(Bb + (rb - 2) * DPU, m[0], tsc);
    hmin8p(Bb + (rb - 1) * DPU, m[1], tsc);
    hmin8p(Bb + (rb + 0) * DPU, m[2], sc[0]);
    erode8<EDGE>(m[0], m[1], m[2], (unsigned)(gy0 - 1) < (unsigned)H, eok, e);
    hmax8(e, hx[0], ec_nxt);
    hmin8p(Bb + (rb + 1) * DPU, m[0], sc[1]);
    erode8<EDGE>(m[1], m[2], m[0], true, eok, e);
    hmax8(e, hx[1], ec_cur);
#pragma unroll
    for (int k = 0; k < 4; k++) {
        hmin8p(Bb + (rb + 2 + k) * DPU, m[(k + 1) % 3], sc[(2 + k) % 3]);
        erode8<EDGE>(m[(k + 2) % 3], m[k % 3], m[(k + 1) % 3],
                     (unsigned)(gy0 + k + 1) < (unsigned)H, eok, e);
        hmax8(e, hx[(k + 2) % 3], ec_nxt);
        uint o[4];
#pragma unroll
        for (int p = 0; p < 4; p++) {
            uint t = pmax(hx[k % 3][p], pmax(hx[(k + 1) % 3][p], hx[(k + 2) % 3][p]));
            o[p] = upd_pair(sc[k % 3][p], ec_cur[p], t);
        }
        if (TOREG) {
#pragma unroll
            for (int p = 0; p < 4; p++) oreg[4 * k + p] = o[p];
        } else {
            *(uint4*)(gdst + (size_t)(gy0 + k) * W + X) = make_uint4(o[0], o[1], o[2], o[3]);
        }
#pragma unroll
        for (int p = 0; p < 4; p++) ec_cur[p] = ec_nxt[p];
    }
}

// Fill packed-fp16 LDS A (k_first geometry) from fp32 source (optional sigmoid);
// fuse dice partials over the 64x128 interior (fp32 pre-pack -> exact dice).
// Batched 2 x 3 load-then-store (MLP latency hiding).
template<bool EDGE, int SIG>
__device__ float2 fillA_f32(uint* __restrict__ A, const float* __restrict__ src,
                            const float* __restrict__ tgt,
                            int tileX, int tileY, int tid) {
    float a = 0.0f, b = 0.0f;
#pragma unroll
    for (int hf = 0; hf < 2; hf++) {
        float4 v0[3], v1[3], t0[3], t1[3];
        bool ld[3];
#pragma unroll
        for (int j = 0; j < 3; j++) {
            const int i = tid + 256 * (3 * hf + j);
            const int r = i / 18;
            const int q = i - 18 * r;
            const int gy = tileY + r - 4;
            const int gx = tileX - 8 + 8 * q;
            bool ok = (i < FILLN);
            if (EDGE) ok = ok && (r < 72) && ((unsigned)gy < (unsigned)H) &&
                           ((unsigned)gx < (unsigned)W);
            ld[j] = ok;
            if (ok) {
                const float* sp = src + (size_t)gy * W + gx;
                v0[j] = *(const float4*)(sp);
                v1[j] = *(const float4*)(sp + 4);
                if (SIG) {
                    const float* tp = tgt + (size_t)gy * W + gx;
                    t0[j] = *(const float4*)(tp);
                    t1[j] = *(const float4*)(tp + 4);
                }
            }
        }
#pragma unroll
        for (int j = 0; j < 3; j++) {
            const int i = tid + 256 * (3 * hf + j);
            const int r = i / 18;
            const int q = i - 18 * r;
            if (i < FILLN) {
                uint4 w = make_uint4(PINF2, PINF2, PINF2, PINF2);
                if (ld[j]) {
                    float4 f0 = v0[j], f1 = v1[j];
                    if (SIG) {
                        f0.x = 1.0f / (1.0f + __expf(-f0.x));
                        f0.y = 1.0f / (1.0f + __expf(-f0.y));
                        f0.z = 1.0f / (1.0f + __expf(-f0.z));
                        f0.w = 1.0f / (1.0f + __expf(-f0.w));
                        f1.x = 1.0f / (1.0f + __expf(-f1.x));
                        f1.y = 1.0f / (1.0f + __expf(-f1.y));
                        f1.z = 1.0f / (1.0f + __expf(-f1.z));
                        f1.w = 1.0f / (1.0f + __expf(-f1.w));
                    }
                    if (((unsigned)(r - 4) < 64u) && ((unsigned)(q - 1) < 16u)) {
                        if (SIG) {
                            a += f0.x * t0[j].x + f0.y * t0[j].y + f0.z * t0[j].z +
                                 f0.w * t0[j].w + f1.x * t1[j].x + f1.y * t1[j].y +
                                 f1.z * t1[j].z + f1.w * t1[j].w;
                            b += f0.x + f0.y + f0.z + f0.w + f1.x + f1.y + f1.z + f1.w;
                        } else {
                            a += f0.x + f0.y + f0.z + f0.w + f1.x + f1.y + f1.z + f1.w;
                        }
                    }
                    w.x = pack2(f0.x, f0.y); w.y = pack2(f0.z, f0.w);
                    w.z = pack2(f1.x, f1.y); w.w = pack2(f1.z, f1.w);
                }
                *(uint4*)(A + r * APU + 4 * q) = w;
            }
        }
    }
    return make_float2(a, b);
}

// DMA fill of A4 (fused geometry). Source rows clamped into the image
// (replicate = SAME-pad-equivalent through masked erosion); fully-OOB x-slots
// (8-aligned, never straddling) write +inf directly. Pad rows 80,81 untouched
// (read only by guarded-out strip outputs).
__device__ __forceinline__ void fill_dma4(uint* __restrict__ A, const f16* __restrict__ src,
                                          int tileX, int tileY, int tid) {
#pragma unroll
    for (int j = 0; j < 7; j++) {
        const int i = tid + 256 * j;
        if (i < FILL4N) {
            const int r = i / 20;
            const int q = i - 20 * r;
            const int gy = tileY + r - 8;
            const int gx = tileX - 16 + 8 * q;
            if (gx < 0 || gx >= W) {
                *(uint4*)(A + r * A4P + 4 * q) = make_uint4(PINF2, PINF2, PINF2, PINF2);
            } else {
                const int gyc = min(max(gy, 0), H - 1);
                lds_dma16(A + r * A4P + 4 * q, src + (size_t)gyc * W + gx);
            }
        }
    }
}

// 4-iteration chain: A4 -> B4 -> C4(in A4) -> D(in B4) -> out.
// If PRE: issue the next tile's A4 DMA after s3's barrier (A4 dead; drains
// under s4's compute, retired by the caller's next __syncthreads()).
template<bool EDGE, bool TOREG, bool PRE>
__device__ void chain4(uint* __restrict__ A4, uint* __restrict__ B4,
                       int tileX, int tileY, int tid,
                       f16* __restrict__ dst, uint* __restrict__ oreg,
                       const f16* __restrict__ pre) {
    stageN<EDGE, A4P, B4P, 19, 13, 6, 76, 6>(A4, B4, tileX, tileY, tid);
    __syncthreads();
    stageN<EDGE, B4P, C4P, 18, 12, 6, 72, 4>(B4, A4, tileX, tileY, tid);
    __syncthreads();
    stageN<EDGE, C4P, DPU, 17, 14, 5, 68, 2>(A4, B4, tileX, tileY, tid);
    __syncthreads();
    if (PRE) fill_dma4(A4, pre, tileX, tileY, tid);
    stage2<EDGE, TOREG>(B4, tileX, tileY, tid, dst, oreg);
}

__device__ __forceinline__ bool is_edge() {
    return (blockIdx.x == 0) | (blockIdx.x == 3) | (blockIdx.y == 0) | (blockIdx.y == 7);
}

// ---- K1: sigmoid + dice partials (fused in fill) + iters 1,2 ----
__global__ __launch_bounds__(256, 4) void k_first(
    const float* __restrict__ logits, const float* __restrict__ target,
    f16* __restrict__ outb, float* __restrict__ parts0, float* __restrict__ parts1) {
    __shared__ __align__(16) uint A[AROWS * APU];
    __shared__ __align__(16) uint Bu[68 * DPU];
    __shared__ float red[8];
    const int img = blockIdx.z;
    const int tileX = blockIdx.x * 128, tileY = blockIdx.y * 64;
    const int tid = threadIdx.x;
    const bool pred = (img < NPRED);
    const bool edge = is_edge();
    float2 ab;
    if (edge) {
        if (pred) ab = fillA_f32<true, 1>(A, logits + (size_t)img * IMG,
                                          target + (size_t)img * IMG, tileX, tileY, tid);
        else      ab = fillA_f32<true, 0>(A, target + (size_t)(img - NPRED) * IMG,
                                          nullptr, tileX, tileY, tid);
    } else {
        if (pred) ab = fillA_f32<false, 1>(A, logits + (size_t)img * IMG,
                                           target + (size_t)img * IMG, tileX, tileY, tid);
        else      ab = fillA_f32<false, 0>(A, target + (size_t)(img - NPRED) * IMG,
                                           nullptr, tileX, tileY, tid);
    }
    __syncthreads();
    float a = wsum64(ab.x), b = wsum64(ab.y);
    if ((tid & 63) == 0) { red[tid >> 6] = a; red[4 + (tid >> 6)] = b; }
    if (edge) stageN<true, APU, DPU, 17, 14, 5, 68, 2>(A, Bu, tileX, tileY, tid);
    else      stageN<false, APU, DPU, 17, 14, 5, 68, 2>(A, Bu, tileX, tileY, tid);
    __syncthreads();
    if (tid == 0) {
        int bi = blockIdx.z * 32 + blockIdx.y * 4 + blockIdx.x;
        parts0[bi] = red[0] + red[1] + red[2] + red[3];
        parts1[bi] = red[4] + red[5] + red[6] + red[7];
    }
    if (edge) stage2<true, false>(Bu, tileX, tileY, tid, outb + (size_t)img * IMG, nullptr);
    else      stage2<false, false>(Bu, tileX, tileY, tid, outb + (size_t)img * IMG, nullptr);
}

// ---- K2: iters 3-6 in one pass, fp16 buf -> fp16 buf ----
__global__ __launch_bounds__(256, 3) void k_mid4(
    const f16* __restrict__ in, f16* __restrict__ outb) {
    __shared__ __align__(16) uint A4[A4R * A4P];
    __shared__ __align__(16) uint B4[76 * B4P];
    const int img = blockIdx.z;
    const int tileX = blockIdx.x * 128, tileY = blockIdx.y * 64;
    const int tid = threadIdx.x;
    const bool edge = is_edge();
    const f16* src = in + (size_t)img * IMG;
    f16* dst = outb + (size_t)img * IMG;
    fill_dma4(A4, src, tileX, tileY, tid);
    __syncthreads();
    if (edge) chain4<true, false, false>(A4, B4, tileX, tileY, tid, dst, nullptr, nullptr);
    else      chain4<false, false, false>(A4, B4, tileX, tileY, tid, dst, nullptr, nullptr);
}

// ---- K3: iters 7-10 for pred tile AND matching target tile; skel-dice partials.
// Target-tile DMA issues inside chain4 (after s3) to overlap with s4. ----
__global__ __launch_bounds__(256, 3) void k_last4(
    const f16* __restrict__ in, float* __restrict__ pA,
    float* __restrict__ pB, float* __restrict__ pC) {
    __shared__ __align__(16) uint A4[A4R * A4P];
    __shared__ __align__(16) uint B4[76 * B4P];
    __shared__ float red[12];
    const int img = blockIdx.z;                  // 0..31
    const int tileX = blockIdx.x * 128, tileY = blockIdx.y * 64;
    const int tid = threadIdx.x;
    const bool edge = is_edge();
    uint op[16], ot[16];
    const f16* tsrc = in + (size_t)(img + NPRED) * IMG;
    fill_dma4(A4, in + (size_t)img * IMG, tileX, tileY, tid);
    __syncthreads();
    if (edge) {
        chain4<true, true, true>(A4, B4, tileX, tileY, tid, nullptr, op, tsrc);
        __syncthreads();   // drain target DMA; all D-reads of pred retired
        chain4<true, true, false>(A4, B4, tileX, tileY, tid, nullptr, ot, nullptr);
    } else {
        chain4<false, true, true>(A4, B4, tileX, tileY, tid, nullptr, op, tsrc);
        __syncthreads();
        chain4<false, true, false>(A4, B4, tileX, tileY, tid, nullptr, ot, nullptr);
    }
    float a = 0.0f, b = 0.0f, c = 0.0f;
#pragma unroll
    for (int j = 0; j < 16; j++) {
        float2 p = unpack2(op[j]);
        float2 t = unpack2(ot[j]);
        a += p.x * t.x + p.y * t.y;
        b += p.x + p.y;
        c += t.x + t.y;
    }
    a = wsum64(a); b = wsum64(b); c = wsum64(c);
    if ((tid & 63) == 0) {
        red[tid >> 6] = a; red[4 + (tid >> 6)] = b; red[8 + (tid >> 6)] = c;
    }
    __syncthreads();
    if (tid == 0) {
        int bi = img * 32 + blockIdx.y * 4 + blockIdx.x;
        pA[bi] = red[0] + red[1] + red[2] + red[3];
        pB[bi] = red[4] + red[5] + red[6] + red[7];
        pC[bi] = red[8] + red[9] + red[10] + red[11];
    }
}

// ---- single finalize: per-image dice (32 imgs x 32 partials) + final means.
// 1024 threads: t>>5 = image, t&31 = partial slot; shfl width 32 keeps the two
// 32-lane halves of each wave on separate images. ----
__global__ __launch_bounds__(1024) void finalize(
    const float* __restrict__ parts0, const float* __restrict__ parts1,
    const float* __restrict__ pA, const float* __restrict__ pB,
    const float* __restrict__ pC, float* __restrict__ out) {
    __shared__ float sd[64];
    const int t = threadIdx.x;
    const int img = t >> 5;
    const int p = t & 31;
    float inter = wsum32(parts0[img * 32 + p]);
    float sp = wsum32(parts1[img * 32 + p]);
    float st = wsum32(parts0[(NPRED + img) * 32 + p]);
    float i2 = wsum32(pA[img * 32 + p]);
    float sp2 = wsum32(pB[img * 32 + p]);
    float st2 = wsum32(pC[img * 32 + p]);
    if (p == 0) {
        sd[img] = (float)((2.0 * (double)inter + 1e-5) / ((double)sp + (double)st + 1e-5));
        sd[32 + img] = (float)((2.0 * (double)i2 + 1e-5) / ((double)sp2 + (double)st2 + 1e-5));
    }
    __syncthreads();
    if (t < 64) {
        double d = (t < 32) ? (double)sd[t] : 0.0;
        double s2 = (t < 32) ? (double)sd[32 + t] : 0.0;
#pragma unroll
        for (int o = 32; o > 0; o >>= 1) { d += __shfl_down(d, o); s2 += __shfl_down(s2, o); }
        if (t == 0) {
            d *= (1.0 / 32.0); s2 *= (1.0 / 32.0);
            out[0] = (float)(0.5 * (1.0 - d) + 0.5 * (1.0 - s2));
            out[1] = (float)d;
            out[2] = (float)s2;
        }
    }
}

extern "C" void kernel_launch(void* const* d_in, const int* in_sizes, int n_in,
                              void* d_out, int out_size, void* d_ws, size_t ws_size,
                              hipStream_t stream) {
    (void)in_sizes; (void)n_in; (void)out_size; (void)ws_size;
    const float* logits = (const float*)d_in[0];
    const float* target = (const float*)d_in[1];
    float* out = (float*)d_out;
    f16* buf0 = (f16*)d_ws;                         // 64*262144 halves (33.5 MB)
    f16* buf1 = buf0 + (size_t)NIMG * IMG;
    float* parts0 = (float*)(buf1 + (size_t)NIMG * IMG);   // 2048
    float* parts1 = parts0 + 2048;                  // 2048
    float* pA = parts1 + 2048;                      // 1024
    float* pB = pA + 1024;
    float* pC = pB + 1024;

    dim3 blk(256, 1, 1);
    k_first<<<dim3(4, 8, NIMG), blk, 0, stream>>>(logits, target, buf0, parts0, parts1);
    k_mid4<<<dim3(4, 8, NIMG), blk, 0, stream>>>(buf0, buf1);         // iters 3-6
    k_last4<<<dim3(4, 8, NPRED), blk, 0, stream>>>(buf1, pA, pB, pC); // iters 7-10 + partials
    finalize<<<1, 1024, 0, stream>>>(parts0, parts1, pA, pB, pC, out);
}